// Round 1
// baseline (302.150 us; speedup 1.0000x reference)
//
#include <hip/hip_runtime.h>

// C=8, L=4, M=8192, NGEN=16, DEPTH=6, BATCH=4, N=5461
// Level starts: L0:0 L1:1 L2:5 L3:21 L4:85 L5:341 leaves:1365
// Subtree s (0..15) rooted at L2 node 5+s.
//
// Single fused kernel: phase A (logsumexp partials + raw LGB gather),
// counter gate, phase B (bleaf + params), counter gate, phase C (tree).
// Cross-phase data published with agent-scope stores (write-through past
// non-coherent XCD L2); consumers gate on device counters and invalidate
// with __threadfence() before plain loads. Arithmetic identical to the
// 3-kernel version (absmax must stay 0).

// ---- workspace layout (4B units) ----
#define WS_PART   0        // 32768
#define WS_LOGDEN 32768    // 128  [g*8+c]
#define WS_ASP    32896    // 4096 [g*256 + (i*8+k)*4+j]
#define WS_LOGA   36992    // 4096
#define WS_LPI    41088    // 512
#define WS_LSP    41600    // 64
#define WS_BLEAF  41664    // 524288 [g*32768 + p*8 + c]
#define WS_LGB    565952   // 698880 = 64*10920: RAW B rows [b][g][node*8+c], internal nodes
#define WS_XCHG   1264832  // 64*768 per (b,g): [B2 0..128 | Q2 128..256 | B3 256..768]
#define WS_SG     1313984  // 64*16*256  per (b,g): [s][t]
#define WS_PG     1576128  // 64*16*2    per (b,g): [s][{pB,pPi}]
// ---- new: phase/rendezvous counters (zeroed by memset node each launch) ----
#define WS_CNT0   1578176  // 16 sub-counters: phase-A done (sum -> 1024)
#define WS_CNT1   1578208  // 16 sub-counters: phase-B done (sum -> 272)
#define WS_XCNT   1578240  // 256: per (b*16+g) L2-exchange rendezvous (-> 16)
#define WS_SGCNT  1578496  // 256: per (b*16+g) epilogue rendezvous (-> 16)
#define WS_END    1578752

__device__ __forceinline__ int node_id(int nl, int s) {
    if (nl == 0) return 0;
    if (nl < 5)  return nl;
    if (nl == 5) return 5 + s;
    if (nl < 10) return 21 + 4 * s + (nl - 6);
    if (nl < 26) return 85 + 16 * s + (nl - 10);
    return 341 + 64 * s + (nl - 26);
}

__device__ __forceinline__ float up_tt(const float* bp, const float* aspU) {
    float tt = 0.f;
    #pragma unroll
    for (int j = 0; j < 4; j++) {
        float4 lo = *(const float4*)(bp + j * 8);
        float4 hi = *(const float4*)(bp + j * 8 + 4);
        tt += aspU[0 + j] * lo.x + aspU[4 + j] * lo.y + aspU[8 + j] * lo.z + aspU[12 + j] * lo.w
            + aspU[16 + j] * hi.x + aspU[20 + j] * hi.y + aspU[24 + j] * hi.z + aspU[28 + j] * hi.w;
    }
    return tt;
}

__device__ __forceinline__ void down_u(const float* r8, const float* aspD, float* u) {
    u[0] = u[1] = u[2] = u[3] = 0.f;
    #pragma unroll
    for (int i = 0; i < 8; i++) {
        u[0] += aspD[i * 4 + 0] * r8[i];
        u[1] += aspD[i * 4 + 1] * r8[i];
        u[2] += aspD[i * 4 + 2] * r8[i];
        u[3] += aspD[i * 4 + 3] * r8[i];
    }
}

// agent-scope (device-coherent, write-through) store / load
__device__ __forceinline__ void ast(float* p, float v) {
    __hip_atomic_store(p, v, __ATOMIC_RELAXED, __HIP_MEMORY_SCOPE_AGENT);
}
__device__ __forceinline__ unsigned aldu(unsigned* p) {
    return __hip_atomic_load(p, __ATOMIC_RELAXED, __HIP_MEMORY_SCOPE_AGENT);
}

__global__ __launch_bounds__(256, 4) void k_main(const int* __restrict__ labels,
                                                 const float* __restrict__ A,
                                                 const float* __restrict__ B,
                                                 const float* __restrict__ Pi,
                                                 const float* __restrict__ SP,
                                                 float* __restrict__ ws,
                                                 float* __restrict__ out) {
    const int x = blockIdx.x, t = threadIdx.x;
    const int s = x & 15, g = (x >> 4) & 15, b = x >> 8;
    const int c8 = t & 7, lane = t & 63, wv = t >> 6;
    const int bg = b * 16 + g;
    unsigned* wu = (unsigned*)ws;

    // ---- phase C LDS ----
    __shared__ __align__(16) float s_blf[2048];   // aliased as epilogue stage after d5
    __shared__ __align__(16) float s_lgb[720];
    __shared__ __align__(16) float s_lgbM[640];   // s==0 only: nodes 5..84
    __shared__ __align__(16) float s_b5[512], s_q5[512], s_r5[512];
    __shared__ __align__(16) float s_b4[128], s_q4[128], s_r4[128];
    __shared__ __align__(16) float s_b3o[32], s_b3a[512], s_q3[32], s_r3[32];
    __shared__ __align__(16) float s_b2[128], s_q2[128], s_r2[128];
    __shared__ float s_b1[32], s_q1[32], s_r1[32], s_b0[8], s_q0[8];
    __shared__ float s_asp[256], s_lpi[32];
    __shared__ float s_scal[12], s_Alh[4];
    // ---- phase A/B LDS ----
    __shared__ float s_stageA[128];
    __shared__ float s_ld[128], s_pie[512], s_smpi[512];          // bleaf
    __shared__ float s_st[256], s_expA[256], s_spe[4], s_pieP[32]; // params

    // ---- register prefetch for phase C d5 (inputs only; overlaps A/B) ----
    float rL[8];
    {
        const int lbase = b * 5461 + 1365 + s * 256;
        int labq[8];
        #pragma unroll
        for (int it = 0; it < 2; ++it) {
            const int p = (it * 256 + t) >> 3;
            #pragma unroll
            for (int j = 0; j < 4; ++j) labq[it * 4 + j] = labels[lbase + 4 * p + j];
        }
        #pragma unroll
        for (int z = 0; z < 8; ++z)
            rL[z] = B[((size_t)(c8 * 8192) + labq[z]) * 16 + g];
    }

    // ================= phase A: logsumexp partials over B =================
    {
        const int cA = x >> 7, chunk = x & 127;
        const float* Bp = B + ((size_t)(cA * 8192) + chunk * 64) * 16;
        float mx = -3.4e38f, sE = 0.f;
        #pragma unroll
        for (int pass = 0; pass < 4; ++pass) {
            const float v = Bp[pass * 256 + t];
            const float nm = fmaxf(mx, v);
            sE = sE * __expf(mx - nm) + __expf(v - nm);
            mx = nm;
        }
        #pragma unroll
        for (int mk = 16; mk <= 32; mk <<= 1) {
            const float om = __shfl_xor(mx, mk), os = __shfl_xor(sE, mk);
            const float nm = fmaxf(mx, om);
            sE = sE * __expf(mx - nm) + os * __expf(om - nm);
            mx = nm;
        }
        if (lane < 16) { s_stageA[(wv * 16 + lane) * 2] = mx; s_stageA[(wv * 16 + lane) * 2 + 1] = sE; }
        __syncthreads();
        if (t < 16) {
            float M = s_stageA[t * 2], S = s_stageA[t * 2 + 1];
            #pragma unroll
            for (int w = 1; w < 4; ++w) {
                const float om = s_stageA[(w * 16 + t) * 2], os = s_stageA[(w * 16 + t) * 2 + 1];
                const float nm = fmaxf(M, om);
                S = S * __expf(M - nm) + os * __expf(om - nm);
                M = nm;
            }
            ast(&ws[WS_PART + ((t * 8 + cA) * 128 + chunk) * 2],     M);
            ast(&ws[WS_PART + ((t * 8 + cA) * 128 + chunk) * 2 + 1], S);
        }
    }
    // ---- phase A: raw internal-node LGB gather (blocks 0..170) ----
    {
        const int item = x * 256 + t;   // 43680 = 4b * 1365node * 8c
        if (item < 43680) {
            const int bb = item / 10920;
            const int rem = item - bb * 10920;
            const int node = rem >> 3, c = rem & 7;
            const int lv = labels[bb * 5461 + node];
            const float* bp2 = B + ((size_t)(c * 8192) + lv) * 16;
            const float4 q0 = *(const float4*)bp2;
            const float4 q1 = *(const float4*)(bp2 + 4);
            const float4 q2 = *(const float4*)(bp2 + 8);
            const float4 q3 = *(const float4*)(bp2 + 12);
            const float vg[16] = {q0.x,q0.y,q0.z,q0.w, q1.x,q1.y,q1.z,q1.w,
                                  q2.x,q2.y,q2.z,q2.w, q3.x,q3.y,q3.z,q3.w};
            float* dst = ws + WS_LGB + (size_t)bb * (16 * 10920) + (size_t)node * 8 + c;
            #pragma unroll
            for (int gg = 0; gg < 16; ++gg)
                ast(&dst[(size_t)gg * 10920], vg[gg]);
        }
    }
    __syncthreads();                                   // drains all vmem stores
    if (t == 0) atomicAdd(&wu[WS_CNT0 + (x & 15)], 1u);

    // ================= phase B: bleaf (0..255) + params (256..271) =================
    if (x < 272) {
        if (t == 0) {
            for (;;) {
                unsigned tot = 0;
                #pragma unroll
                for (int i = 0; i < 16; ++i) tot += aldu(&wu[WS_CNT0 + i]);
                if (tot >= 1024u) break;
                __builtin_amdgcn_s_sleep(8);
            }
            __threadfence();                           // acquire: invalidate stale L1/L2
        }
        __syncthreads();
        if (x < 256) {
            // ---- bleaf ----
            {
                const int pair = t >> 1, half = t & 1;
                const int c = pair >> 4, gg2 = pair & 15;
                const float* pp = ws + WS_PART + (size_t)(((gg2 * 8 + c) * 128 + half * 64) * 2);
                float M = -3.4e38f, S = 0.f;
                for (int q = 0; q < 64; ++q) {
                    const float om = pp[q * 2], os = pp[q * 2 + 1];
                    const float nm = fmaxf(M, om);
                    S = S * __expf(M - nm) + os * __expf(om - nm);
                    M = nm;
                }
                const float om = __shfl_xor(M, 1), os = __shfl_xor(S, 1);
                const float nm = fmaxf(M, om);
                S = S * __expf(M - nm) + os * __expf(om - nm);
                M = nm;
                if (half == 0) s_ld[c * 16 + gg2] = M + __logf(S);
            }
            s_pie[t] = __expf(Pi[t]);
            s_pie[256 + t] = __expf(Pi[256 + t]);
            __syncthreads();
            #pragma unroll
            for (int h = 0; h < 2; ++h) {
                const int idx = h * 256 + t;
                const int jg = idx & 63;
                float ps = 0.f;
                #pragma unroll
                for (int c2 = 0; c2 < 8; ++c2) ps += s_pie[c2 * 64 + jg];
                s_smpi[idx] = s_pie[idx] / ps;
            }
            __syncthreads();
            const int id = x * 256 + t;
            const int gl = id & 15, p = id >> 4;
            const int pos = p & 3;
            float vals[8], ssum = 0.f;
            #pragma unroll
            for (int c = 0; c < 8; ++c) {
                const float v = s_smpi[(c * 4 + pos) * 16 + gl] *
                    __expf(B[((size_t)(c * 8192) + 1365 + p) * 16 + gl] - s_ld[c * 16 + gl]);
                vals[c] = v; ssum += v;
            }
            const float inv = 1.f / ssum;
            float* o = ws + WS_BLEAF + (size_t)gl * 32768 + (size_t)p * 8;
            #pragma unroll
            for (int c = 0; c < 8; ++c) ast(&o[c], vals[c] * inv);
        } else {
            // ---- params for gp = x-256 ----
            const int gp = x - 256;
            if (t < 128) {
                const int c2 = t >> 4, part = t & 15;
                const float* pp = ws + WS_PART + (size_t)(((gp * 8 + c2) * 128 + part * 8) * 2);
                float M = -3.4e38f, S = 0.f;
                #pragma unroll
                for (int q = 0; q < 8; ++q) {
                    const float om = pp[q * 2], os = pp[q * 2 + 1];
                    const float nm = fmaxf(M, om);
                    S = S * __expf(M - nm) + os * __expf(om - nm);
                    M = nm;
                }
                s_st[t * 2] = M; s_st[t * 2 + 1] = S;
            }
            const float Av = A[t * 16 + gp];
            s_expA[t] = __expf(Av);
            if (t < 4) s_spe[t] = __expf(SP[t * 16 + gp]);
            if (t >= 32 && t < 64) s_pieP[t - 32] = __expf(Pi[(t - 32) * 16 + gp]);
            __syncthreads();
            if (t < 8) {
                float M = s_st[(t * 16) * 2], S = s_st[(t * 16) * 2 + 1];
                #pragma unroll
                for (int q = 1; q < 16; ++q) {
                    const float om = s_st[(t * 16 + q) * 2], os = s_st[(t * 16 + q) * 2 + 1];
                    const float nm = fmaxf(M, om);
                    S = S * __expf(M - nm) + os * __expf(om - nm);
                    M = nm;
                }
                ast(&ws[WS_LOGDEN + gp * 8 + t], M + __logf(S));
            }
            {
                const int kk = (t >> 2) & 7, jj = t & 3;
                float sumA = 0.f;
                #pragma unroll
                for (int i = 0; i < 8; ++i) sumA += s_expA[(i * 8 + kk) * 4 + jj];
                const float sps = s_spe[0] + s_spe[1] + s_spe[2] + s_spe[3];
                ast(&ws[WS_ASP + gp * 256 + t],  s_expA[t] / sumA * (s_spe[jj] / sps));
                ast(&ws[WS_LOGA + gp * 256 + t], Av - __logf(sumA));
                if (t < 4) ast(&ws[WS_LSP + gp * 4 + t], SP[t * 16 + gp] - __logf(sps));
                if (t < 32) {
                    float ps = 0.f;
                    #pragma unroll
                    for (int i2 = 0; i2 < 8; ++i2) ps += s_pieP[i2 * 4 + (t & 3)];
                    ast(&ws[WS_LPI + gp * 32 + t], Pi[t * 16 + gp] - __logf(ps));
                }
            }
        }
        __syncthreads();                               // drain phase-B stores
        if (t == 0) atomicAdd(&wu[WS_CNT1 + (x & 15)], 1u);
    }

    // ================= phase C gate =================
    if (t == 0) {
        for (;;) {
            unsigned tot = 0;
            #pragma unroll
            for (int i = 0; i < 16; ++i) tot += aldu(&wu[WS_CNT1 + i]);
            if (tot >= 272u) break;
            __builtin_amdgcn_s_sleep(8);
        }
        __threadfence();                               // acquire: invalidate stale L1/L2
    }
    __syncthreads();

    // ================= phase C: fused up + exchange + down + finalize =================
    const float ldc8 = ws[WS_LOGDEN + g * 8 + c8];

    s_asp[t] = ws[WS_ASP + g * 256 + t];
    if (t < 32) s_lpi[t] = ws[WS_LPI + g * 32 + t];
    {
        const float4* bsrc = (const float4*)(ws + WS_BLEAF + (size_t)g * 32768 + (size_t)s * 2048);
        ((float4*)s_blf)[t] = bsrc[t];
        ((float4*)s_blf)[t + 256] = bsrc[t + 256];
    }
    const float* lgbP = ws + WS_LGB + (size_t)bg * 10920;
    // internal-lgb: dense loads; c = q&7 == t&7 == c8, so subtract ldc8
    #pragma unroll
    for (int it = 0; it < 3; ++it) {
        const int q = it * 256 + t;
        if (q < 720) {
            const int nl = q >> 3;
            s_lgb[q] = lgbP[node_id(nl, s) * 8 + c8] - ldc8;
        }
    }
    if (s == 0) {                                 // nodes 5..84: contiguous; idx&7 == c8
        #pragma unroll
        for (int it = 0; it < 3; ++it) {
            const int idx = it * 256 + t;
            if (idx < 640) s_lgbM[idx] = lgbP[40 + idx] - ldc8;
        }
    }
    __syncthreads();

    float aspR[32];   // UP layout: [k*4+j] = A_SP[i=c8,k,j]
    #pragma unroll
    for (int k = 0; k < 8; ++k)
        #pragma unroll
        for (int j = 0; j < 4; ++j) aspR[k * 4 + j] = s_asp[(c8 * 8 + k) * 4 + j];

    // ---- up-sweep (own subtree), all state in LDS ----
    #pragma unroll
    for (int it = 0; it < 2; ++it) {              // L5: 64 nodes
        const int p = (it * 256 + t) >> 3;
        const float tt = up_tt(s_blf + p * 32, aspR);
        const float bu = tt * __expf(s_lgb[(26 + p) * 8 + c8]);
        float ssum = bu;
        ssum += __shfl_xor(ssum, 1); ssum += __shfl_xor(ssum, 2); ssum += __shfl_xor(ssum, 4);
        const float beta = bu / ssum;
        s_b5[p * 8 + c8] = beta; s_q5[p * 8 + c8] = beta / tt;
    }
    __syncthreads();
    if (t < 128) {                                // L4: 16
        const int p = t >> 3;
        const float tt = up_tt(s_b5 + p * 32, aspR);
        const float bu = tt * __expf(s_lgb[(10 + p) * 8 + c8]);
        float ssum = bu;
        ssum += __shfl_xor(ssum, 1); ssum += __shfl_xor(ssum, 2); ssum += __shfl_xor(ssum, 4);
        const float beta = bu / ssum;
        s_b4[p * 8 + c8] = beta; s_q4[p * 8 + c8] = beta / tt;
    }
    __syncthreads();
    if (t < 32) {                                 // L3: 4
        const int p = t >> 3;
        const float tt = up_tt(s_b4 + p * 32, aspR);
        const float bu = tt * __expf(s_lgb[(6 + p) * 8 + c8]);
        float ssum = bu;
        ssum += __shfl_xor(ssum, 1); ssum += __shfl_xor(ssum, 2); ssum += __shfl_xor(ssum, 4);
        const float beta = bu / ssum;
        s_b3o[p * 8 + c8] = beta; s_q3[p * 8 + c8] = beta / tt;
    }
    __syncthreads();
    float* X = ws + WS_XCHG + (size_t)bg * 768;
    if (t < 8) {                                  // L2 -> exchange (agent stores)
        const float tt = up_tt(s_b3o, aspR);
        const float bu = tt * __expf(s_lgb[5 * 8 + c8]);
        float ssum = bu;
        ssum += __shfl_xor(ssum, 1); ssum += __shfl_xor(ssum, 2); ssum += __shfl_xor(ssum, 4);
        const float beta = bu / ssum;
        ast(&X[s * 8 + c8], beta);
        ast(&X[128 + s * 8 + c8], beta / tt);
    }
    if (t < 32) ast(&X[256 + s * 32 + t], s_b3o[t]);
    __syncthreads();                              // drain X stores
    if (t == 0) {
        atomicAdd(&wu[WS_XCNT + bg], 1u);
        while (aldu(&wu[WS_XCNT + bg]) < 16u) __builtin_amdgcn_s_sleep(2);
    }
    __syncthreads();
    {
        const float v = X[t];                     // plain loads: fresh (written-through)
        if (t < 128) s_b2[t] = v; else s_q2[t - 128] = v;
        if (s == 0) {
            s_b3a[t] = X[256 + t];
            s_b3a[256 + t] = X[512 + t];
        }
    }
    __syncthreads();

    // ---- middle up (replicated per subtree) ----
    if (t < 32) {                                 // L1
        const int p = t >> 3;
        const float tt = up_tt(s_b2 + p * 32, aspR);
        const float bu = tt * __expf(s_lgb[(1 + p) * 8 + c8]);
        float ssum = bu;
        ssum += __shfl_xor(ssum, 1); ssum += __shfl_xor(ssum, 2); ssum += __shfl_xor(ssum, 4);
        s_b1[p * 8 + c8] = bu / ssum;
        s_q1[p * 8 + c8] = (bu / ssum) / tt;
    }
    __syncthreads();
    if (t < 8) {                                  // L0
        const float tt = up_tt(s_b1, aspR);
        const float bu = tt * __expf(s_lgb[c8]);
        float ssum = bu;
        ssum += __shfl_xor(ssum, 1); ssum += __shfl_xor(ssum, 2); ssum += __shfl_xor(ssum, 4);
        s_b0[c8] = bu / ssum;
        s_q0[c8] = (bu / ssum) / tt;
    }
    __syncthreads();

    #pragma unroll
    for (int i = 0; i < 8; ++i)                   // DOWN layout: [i*4+j] = A_SP[i,k=c8,j]
        #pragma unroll
        for (int j = 0; j < 4; ++j) aspR[i * 4 + j] = s_asp[(i * 8 + c8) * 4 + j];

    float pB = 0.f, pPi = 0.f;
    float Sacc[32];
    #pragma unroll
    for (int z = 0; z < 32; z++) Sacc[z] = 0.f;

    // d=0
    if (t < 8) {
        float r8[8], u[4];
        #pragma unroll
        for (int i = 0; i < 8; i++) r8[i] = s_q0[i];
        down_u(r8, aspR, u);
        #pragma unroll
        for (int j = 0; j < 4; j++) s_r1[j * 8 + c8] = s_q1[j * 8 + c8] * u[j];
        if (s == 0) {
            pB += s_b0[c8] * s_lgb[c8];
            #pragma unroll
            for (int j = 0; j < 4; j++) {
                const float bc = s_b1[j * 8 + c8];
                pB += bc * u[j] * s_lgb[(1 + j) * 8 + c8];
                #pragma unroll
                for (int i = 0; i < 8; i++) Sacc[i * 4 + j] += r8[i] * bc;
            }
        }
    }
    __syncthreads();
    // d=1
    if (t < 32) {
        const int p = t >> 3;
        float r8[8], u[4];
        #pragma unroll
        for (int i = 0; i < 8; i++) r8[i] = s_r1[p * 8 + i];
        down_u(r8, aspR, u);
        #pragma unroll
        for (int j = 0; j < 4; j++) {
            const int ch = 4 * p + j;
            s_r2[ch * 8 + c8] = s_q2[ch * 8 + c8] * u[j];
            if (s == 0) {
                const float bc = s_b2[ch * 8 + c8];
                pB += bc * u[j] * s_lgbM[ch * 8 + c8];
                #pragma unroll
                for (int i = 0; i < 8; i++) Sacc[i * 4 + j] += r8[i] * bc;
            }
        }
    }
    __syncthreads();
    // d=2
    if (t < 128) {
        const int p = t >> 3;
        float r8[8], u[4];
        #pragma unroll
        for (int i = 0; i < 8; i++) r8[i] = s_r2[p * 8 + i];
        down_u(r8, aspR, u);
        #pragma unroll
        for (int j = 0; j < 4; j++) {
            const int ch = 4 * p + j;
            if (p == s) s_r3[j * 8 + c8] = s_q3[j * 8 + c8] * u[j];
            if (s == 0) {
                const float bc = s_b3a[ch * 8 + c8];
                pB += bc * u[j] * s_lgbM[(16 + ch) * 8 + c8];
                #pragma unroll
                for (int i = 0; i < 8; i++) Sacc[i * 4 + j] += r8[i] * bc;
            }
        }
    }
    __syncthreads();
    // d=3
    if (t < 32) {
        const int p = t >> 3;
        float r8[8], u[4];
        #pragma unroll
        for (int i = 0; i < 8; i++) r8[i] = s_r3[p * 8 + i];
        down_u(r8, aspR, u);
        #pragma unroll
        for (int j = 0; j < 4; j++) {
            const int ch = 4 * p + j;
            const float bc = s_b4[ch * 8 + c8];
            pB += bc * u[j] * s_lgb[(10 + ch) * 8 + c8];
            s_r4[ch * 8 + c8] = s_q4[ch * 8 + c8] * u[j];
            #pragma unroll
            for (int i = 0; i < 8; i++) Sacc[i * 4 + j] += r8[i] * bc;
        }
    }
    __syncthreads();
    // d=4
    if (t < 128) {
        const int p = t >> 3;
        float r8[8], u[4];
        #pragma unroll
        for (int i = 0; i < 8; i++) r8[i] = s_r4[p * 8 + i];
        down_u(r8, aspR, u);
        #pragma unroll
        for (int j = 0; j < 4; j++) {
            const int ch = 4 * p + j;
            const float bc = s_b5[ch * 8 + c8];
            pB += bc * u[j] * s_lgb[(26 + ch) * 8 + c8];
            s_r5[ch * 8 + c8] = s_q5[ch * 8 + c8] * u[j];
            #pragma unroll
            for (int i = 0; i < 8; i++) Sacc[i * 4 + j] += r8[i] * bc;
        }
    }
    __syncthreads();
    // d=5 (leaves): leaf-lgb from registers
    #pragma unroll
    for (int it = 0; it < 2; ++it) {
        const int p = (it * 256 + t) >> 3;
        float r8[8], u[4];
        #pragma unroll
        for (int i = 0; i < 8; i++) r8[i] = s_r5[p * 8 + i];
        down_u(r8, aspR, u);
        #pragma unroll
        for (int j = 0; j < 4; j++) {
            const int q = 4 * p + j;
            const float bc = s_blf[q * 8 + c8];
            const float e6 = bc * u[j];
            pB += e6 * (rL[it * 4 + j] - ldc8);
            pPi += e6 * s_lpi[c8 * 4 + j];
            #pragma unroll
            for (int i = 0; i < 8; i++) Sacc[i * 4 + j] += r8[i] * bc;
        }
    }

    // ---- epilogue: reduce, publish per-s slots, counter rendezvous ----
    #pragma unroll
    for (int z = 0; z < 32; z++) {
        float v = Sacc[z];
        v += __shfl_xor(v, 8);
        v += __shfl_xor(v, 16);
        v += __shfl_xor(v, 32);
        Sacc[z] = v;
    }
    #pragma unroll
    for (int m = 1; m < 64; m <<= 1) { pB += __shfl_xor(pB, m); pPi += __shfl_xor(pPi, m); }
    float* s_stage = s_blf;                       // alias: blf dead after d5
    __syncthreads();
    if (lane < 8) {
        #pragma unroll
        for (int z = 0; z < 32; z++)
            s_stage[wv * 256 + ((z >> 2) * 8 + lane) * 4 + (z & 3)] = Sacc[z];
    }
    if (lane == 0) { s_scal[wv] = pB; s_scal[4 + wv] = pPi; }
    __syncthreads();
    {
        const float TS = s_stage[t] + s_stage[256 + t] + s_stage[512 + t] + s_stage[768 + t];
        float* SgW = ws + WS_SG + ((size_t)bg * 16 + s) * 256;
        ast(&SgW[t], TS);
        float* PgW = ws + WS_PG + ((size_t)bg * 16 + s) * 2;
        if (t == 0) ast(&PgW[0], s_scal[0] + s_scal[1] + s_scal[2] + s_scal[3]);
        if (t == 1) ast(&PgW[1], s_scal[4] + s_scal[5] + s_scal[6] + s_scal[7]);
    }
    __syncthreads();                              // drain SG/PG stores
    if (t == 0) atomicAdd(&wu[WS_SGCNT + bg], 1u);

    // ---- finalize: block s==15 gates on counter, then plain loads ----
    if (s == 15) {
        if (t == 0) {
            while (aldu(&wu[WS_SGCNT + bg]) < 16u) __builtin_amdgcn_s_sleep(2);
        }
        __syncthreads();
        if (t < 4) s_Alh[t] = 0.f;
        float Ssum = 0.f;
        float* SgB = ws + WS_SG + (size_t)bg * 4096;
        #pragma unroll
        for (int sp = 0; sp < 16; ++sp)
            Ssum += SgB[sp * 256 + t];
        if (t < 2) {
            float* PgB = ws + WS_PG + (size_t)bg * 32;
            float tot = 0.f;
            #pragma unroll
            for (int sp = 0; sp < 16; ++sp)
                tot += PgB[sp * 2 + t];
            s_scal[8 + t] = tot;
        }
        __syncthreads();
        const float val = s_asp[t] * Ssum;
        atomicAdd(&s_Alh[t & 3], val * ws[WS_LOGA + g * 256 + t]);
        __syncthreads();
        out[(size_t)b * 4096 + t * 16 + g] =
            -(s_Alh[t & 3] + s_scal[8] + s_scal[9] + val * ws[WS_LSP + g * 4 + (t & 3)]);
    }
}

extern "C" void kernel_launch(void* const* d_in, const int* in_sizes, int n_in,
                              void* d_out, int out_size, void* d_ws, size_t ws_size,
                              hipStream_t stream) {
    (void)in_sizes; (void)n_in; (void)out_size; (void)ws_size;
    const int* labels = (const int*)d_in[0];
    const float* A  = (const float*)d_in[1];
    const float* B  = (const float*)d_in[2];
    const float* Pi = (const float*)d_in[3];
    const float* SP = (const float*)d_in[4];
    float* ws = (float*)d_ws;
    float* out = (float*)d_out;

    // zero the phase/rendezvous counters (graph-capturable memset node)
    hipMemsetAsync((char*)d_ws + (size_t)WS_CNT0 * 4, 0, (size_t)(WS_END - WS_CNT0) * 4, stream);
    hipLaunchKernelGGL(k_main, dim3(1024), dim3(256), 0, stream, labels, A, B, Pi, SP, ws, out);
}